// Round 3
// baseline (511.978 us; speedup 1.0000x reference)
//
#include <hip/hip_runtime.h>
#include <hip/hip_bf16.h>

#define IN_FT  128
#define OUT_FT 32
#define GEMM_ROWS 64
#define PITCH  132
#define BROWS    256              // rows per bucket (power of 2)
#define MAXBK    512              // max buckets supported
#define BIN_BLOCKS 256

// -------------------- support = seq @ weight --------------------
__global__ __launch_bounds__(256) void gcn_gemm(const float* __restrict__ seq,
                                                const float* __restrict__ w,
                                                float* __restrict__ sup,
                                                int n) {
    __shared__ __align__(16) float lw[IN_FT * OUT_FT];
    __shared__ __align__(16) float ls[GEMM_ROWS * PITCH];

    const int tid = threadIdx.x;
    for (int i = tid; i < (IN_FT * OUT_FT) / 4; i += 256)
        ((float4*)lw)[i] = ((const float4*)w)[i];

    const int base = blockIdx.x * GEMM_ROWS;
    for (int i = tid; i < GEMM_ROWS * (IN_FT / 4); i += 256) {
        int r  = i >> 5;
        int kc = i & 31;
        int row = base + r;
        float4 v = make_float4(0.f, 0.f, 0.f, 0.f);
        if (row < n)
            v = ((const float4*)(seq + (size_t)row * IN_FT))[kc];
        *(float4*)&ls[r * PITCH + kc * 4] = v;
    }
    __syncthreads();

    const int cg = (tid & 7) * 4;
    const int rp = tid >> 3;
    const int r0 = rp * 2, r1 = r0 + 1;

    float4 acc0 = make_float4(0.f, 0.f, 0.f, 0.f);
    float4 acc1 = make_float4(0.f, 0.f, 0.f, 0.f);

#define FMA4(acc, s, wv) \
    acc.x = fmaf((s), (wv).x, acc.x); \
    acc.y = fmaf((s), (wv).y, acc.y); \
    acc.z = fmaf((s), (wv).z, acc.z); \
    acc.w = fmaf((s), (wv).w, acc.w);

    for (int k = 0; k < IN_FT; k += 4) {
        float4 s0 = *(const float4*)&ls[r0 * PITCH + k];
        float4 s1 = *(const float4*)&ls[r1 * PITCH + k];
        float4 w0 = *(const float4*)&lw[(k + 0) * OUT_FT + cg];
        float4 w1 = *(const float4*)&lw[(k + 1) * OUT_FT + cg];
        float4 w2 = *(const float4*)&lw[(k + 2) * OUT_FT + cg];
        float4 w3 = *(const float4*)&lw[(k + 3) * OUT_FT + cg];
        FMA4(acc0, s0.x, w0); FMA4(acc0, s0.y, w1);
        FMA4(acc0, s0.z, w2); FMA4(acc0, s0.w, w3);
        FMA4(acc1, s1.x, w0); FMA4(acc1, s1.y, w1);
        FMA4(acc1, s1.z, w2); FMA4(acc1, s1.w, w3);
    }
#undef FMA4

    int row0 = base + r0;
    if (row0 < n) *(float4*)&sup[(size_t)row0 * OUT_FT + cg] = acc0;
    int row1 = base + r1;
    if (row1 < n) *(float4*)&sup[(size_t)row1 * OUT_FT + cg] = acc1;
}

// -------------------- bucket histogram (block-local then global) ------------
__global__ __launch_bounds__(256) void gcn_bhist(const int* __restrict__ erow,
                                                 int* __restrict__ gcnt,
                                                 int ne, int nb) {
    __shared__ int lh[MAXBK];
    int t = threadIdx.x;
    for (int i = t; i < MAXBK; i += 256) lh[i] = 0;
    __syncthreads();
    for (int e = blockIdx.x * 256 + t; e < ne; e += gridDim.x * 256)
        atomicAdd(&lh[erow[e] >> 8], 1);
    __syncthreads();
    for (int b = t; b < nb; b += 256)
        if (lh[b]) atomicAdd(&gcnt[b], lh[b]);
}

// -------------------- scan bucket counts (single block, 512 thr) ------------
__global__ __launch_bounds__(512) void gcn_bscan(const int* __restrict__ gcnt,
                                                 int* __restrict__ start,
                                                 int* __restrict__ cursor,
                                                 int nb) {
    __shared__ int s[MAXBK];
    int t = threadIdx.x;
    int v = (t < nb) ? gcnt[t] : 0;
    s[t] = v;
    __syncthreads();
    for (int off = 1; off < MAXBK; off <<= 1) {
        int x = (t >= off) ? s[t - off] : 0;
        __syncthreads();
        s[t] += x;
        __syncthreads();
    }
    if (t < nb) {
        int ex = s[t] - v;
        start[t]  = ex;
        cursor[t] = ex;
        if (t == nb - 1) start[nb] = s[t];
    }
}

// -------------------- bin edges into packed bucket regions ------------------
// packed record: x = (row_local:8 << 17) | col:17 ; y = bits(val)
__global__ __launch_bounds__(256) void gcn_bin(const int* __restrict__ erow,
                                               const int* __restrict__ ecol,
                                               const float* __restrict__ eval,
                                               int* __restrict__ cursor,
                                               uint2* __restrict__ packed,
                                               int ne, int nb, int chunk) {
    __shared__ int lh[MAXBK];
    __shared__ int lb[MAXBK];
    int t = threadIdx.x;
    int beg = blockIdx.x * chunk;
    int end = min(beg + chunk, ne);
    for (int i = t; i < MAXBK; i += 256) lh[i] = 0;
    __syncthreads();
    for (int e = beg + t; e < end; e += 256)
        atomicAdd(&lh[erow[e] >> 8], 1);
    __syncthreads();
    for (int b = t; b < nb; b += 256)
        lb[b] = lh[b] ? atomicAdd(&cursor[b], lh[b]) : 0;
    __syncthreads();
    for (int e = beg + t; e < end; e += 256) {
        int r = erow[e];
        int b = r >> 8;
        int p = atomicAdd(&lb[b], 1);
        packed[p] = make_uint2(((unsigned)(r & (BROWS - 1)) << 17) | (unsigned)ecol[e],
                               __float_as_uint(eval[e]));
    }
}

// -------------------- accumulate per bucket in LDS, fused relu --------------
__global__ __launch_bounds__(512) void gcn_acc(const int* __restrict__ start,
                                               const uint2* __restrict__ packed,
                                               const float* __restrict__ sup,
                                               float* __restrict__ out, int n) {
    __shared__ __align__(16) float acc[BROWS * OUT_FT];   // 32 KB
    int t = threadIdx.x;
    for (int i = t; i < (BROWS * OUT_FT) / 4; i += 512)
        ((float4*)acc)[i] = make_float4(0.f, 0.f, 0.f, 0.f);
    __syncthreads();

    int b   = blockIdx.x;
    int beg = start[b];
    int end = start[b + 1];
    int hw  = t >> 5;        // half-wave id 0..15
    int col = t & 31;

    for (int j = beg + hw * 4; j < end; j += 64) {
        int m = end - j;
        uint2 r0, r1, r2, r3;
        r0 = packed[j];
        if (m > 1) r1 = packed[j + 1];
        if (m > 2) r2 = packed[j + 2];
        if (m > 3) r3 = packed[j + 3];
        float s0 = sup[(size_t)(r0.x & 0x1FFFF) * OUT_FT + col];
        float s1 = (m > 1) ? sup[(size_t)(r1.x & 0x1FFFF) * OUT_FT + col] : 0.f;
        float s2 = (m > 2) ? sup[(size_t)(r2.x & 0x1FFFF) * OUT_FT + col] : 0.f;
        float s3 = (m > 3) ? sup[(size_t)(r3.x & 0x1FFFF) * OUT_FT + col] : 0.f;
        atomicAdd(&acc[(r0.x >> 17) * OUT_FT + col], __uint_as_float(r0.y) * s0);
        if (m > 1) atomicAdd(&acc[(r1.x >> 17) * OUT_FT + col], __uint_as_float(r1.y) * s1);
        if (m > 2) atomicAdd(&acc[(r2.x >> 17) * OUT_FT + col], __uint_as_float(r2.y) * s2);
        if (m > 3) atomicAdd(&acc[(r3.x >> 17) * OUT_FT + col], __uint_as_float(r3.y) * s3);
    }
    __syncthreads();

    int base_row = b << 8;
    for (int i = t; i < (BROWS * OUT_FT) / 4; i += 512) {
        int rl  = i >> 3;                 // 8 float4 per row
        int row = base_row + rl;
        if (row < n) {
            float4 v = ((float4*)acc)[i];
            v.x = fmaxf(v.x, 0.f); v.y = fmaxf(v.y, 0.f);
            v.z = fmaxf(v.z, 0.f); v.w = fmaxf(v.w, 0.f);
            ((float4*)(out + (size_t)row * OUT_FT))[i & 7] = v;
        }
    }
}

// -------------------- fallback path (round-1) --------------------
__global__ __launch_bounds__(256) void gcn_scatter(const int* __restrict__ erow,
                                                   const int* __restrict__ ecol,
                                                   const float* __restrict__ eval,
                                                   const float* __restrict__ sup,
                                                   float* __restrict__ out,
                                                   int n_edges) {
    long long g = (long long)blockIdx.x * 256 + threadIdx.x;
    int e = (int)(g >> 5);
    int c = (int)(g & 31);
    if (e >= n_edges) return;
    atomicAdd(out + (size_t)erow[e] * OUT_FT + c,
              eval[e] * sup[(size_t)ecol[e] * OUT_FT + c]);
}

__global__ __launch_bounds__(256) void gcn_relu(float4* __restrict__ out, int n4) {
    int i = blockIdx.x * 256 + threadIdx.x;
    if (i < n4) {
        float4 v = out[i];
        v.x = fmaxf(v.x, 0.f); v.y = fmaxf(v.y, 0.f);
        v.z = fmaxf(v.z, 0.f); v.w = fmaxf(v.w, 0.f);
        out[i] = v;
    }
}

extern "C" void kernel_launch(void* const* d_in, const int* in_sizes, int n_in,
                              void* d_out, int out_size, void* d_ws, size_t ws_size,
                              hipStream_t stream) {
    const float* seq  = (const float*)d_in[0];
    const float* w    = (const float*)d_in[1];
    const int*   erow = (const int*)d_in[2];
    const int*   ecol = (const int*)d_in[3];
    const float* eval = (const float*)d_in[4];
    float* out = (float*)d_out;

    const int n_nodes = in_sizes[0] / IN_FT;
    const int n_edges = in_sizes[2];
    const int nb = (n_nodes + BROWS - 1) / BROWS;

    // ---- workspace layout ----
    char* ws = (char*)d_ws;
    size_t off = 0;
    auto alloc = [&](size_t bytes) {
        char* p = ws + off;
        off += (bytes + 255) & ~(size_t)255;
        return p;
    };
    float* sup    = (float*)alloc((size_t)n_nodes * OUT_FT * sizeof(float));
    int*   gcnt   = (int*)  alloc(MAXBK * sizeof(int));
    int*   start  = (int*)  alloc((MAXBK + 1) * sizeof(int));
    int*   cursor = (int*)  alloc(MAXBK * sizeof(int));
    uint2* packed = (uint2*)alloc((size_t)n_edges * sizeof(uint2));
    bool have_ws = (off <= ws_size) && (nb <= MAXBK);

    // 1) support = seq @ weight
    int gemm_blocks = (n_nodes + GEMM_ROWS - 1) / GEMM_ROWS;
    gcn_gemm<<<gemm_blocks, 256, 0, stream>>>(seq, w, sup, n_nodes);

    if (have_ws) {
        hipMemsetAsync(gcnt, 0, MAXBK * sizeof(int), stream);
        gcn_bhist<<<BIN_BLOCKS, 256, 0, stream>>>(erow, gcnt, n_edges, nb);
        gcn_bscan<<<1, 512, 0, stream>>>(gcnt, start, cursor, nb);
        int chunk = (n_edges + BIN_BLOCKS - 1) / BIN_BLOCKS;
        gcn_bin<<<BIN_BLOCKS, 256, 0, stream>>>(erow, ecol, eval, cursor,
                                                packed, n_edges, nb, chunk);
        gcn_acc<<<nb, 512, 0, stream>>>(start, packed, sup, out, n_nodes);
    } else {
        hipMemsetAsync(d_out, 0, (size_t)out_size * sizeof(float), stream);
        long long work = (long long)n_edges * OUT_FT;
        gcn_scatter<<<(int)((work + 255) / 256), 256, 0, stream>>>(
            erow, ecol, eval, sup, out, n_edges);
        int n4 = out_size / 4;
        gcn_relu<<<(n4 + 255) / 256, 256, 0, stream>>>((float4*)out, n4);
    }
}

// Round 4
// 443.242 us; speedup vs baseline: 1.1551x; 1.1551x over previous
//
#include <hip/hip_runtime.h>
#include <hip/hip_bf16.h>

#define IN_FT  128
#define OUT_FT 32
#define GEMM_ROWS 64
#define PITCH  132

// float -> bf16 (round-to-nearest-even)
__device__ __forceinline__ unsigned short f2bf(float x) {
    union { float f; unsigned u; } v; v.f = x;
    unsigned r = v.u + 0x7FFFu + ((v.u >> 16) & 1u);
    return (unsigned short)(r >> 16);
}

// -------------------- support(bf16) = seq @ weight --------------------
__global__ __launch_bounds__(256) void gcn_gemm(const float* __restrict__ seq,
                                                const float* __restrict__ w,
                                                unsigned short* __restrict__ supb,
                                                int n) {
    __shared__ __align__(16) float lw[IN_FT * OUT_FT];
    __shared__ __align__(16) float ls[GEMM_ROWS * PITCH];

    const int tid = threadIdx.x;
    for (int i = tid; i < (IN_FT * OUT_FT) / 4; i += 256)
        ((float4*)lw)[i] = ((const float4*)w)[i];

    const int base = blockIdx.x * GEMM_ROWS;
    for (int i = tid; i < GEMM_ROWS * (IN_FT / 4); i += 256) {
        int r  = i >> 5;
        int kc = i & 31;
        int row = base + r;
        float4 v = make_float4(0.f, 0.f, 0.f, 0.f);
        if (row < n)
            v = ((const float4*)(seq + (size_t)row * IN_FT))[kc];
        *(float4*)&ls[r * PITCH + kc * 4] = v;
    }
    __syncthreads();

    const int cg = (tid & 7) * 4;
    const int rp = tid >> 3;
    const int r0 = rp * 2, r1 = r0 + 1;

    float4 acc0 = make_float4(0.f, 0.f, 0.f, 0.f);
    float4 acc1 = make_float4(0.f, 0.f, 0.f, 0.f);

#define FMA4(acc, s, wv) \
    acc.x = fmaf((s), (wv).x, acc.x); \
    acc.y = fmaf((s), (wv).y, acc.y); \
    acc.z = fmaf((s), (wv).z, acc.z); \
    acc.w = fmaf((s), (wv).w, acc.w);

    for (int k = 0; k < IN_FT; k += 4) {
        float4 s0 = *(const float4*)&ls[r0 * PITCH + k];
        float4 s1 = *(const float4*)&ls[r1 * PITCH + k];
        float4 w0 = *(const float4*)&lw[(k + 0) * OUT_FT + cg];
        float4 w1 = *(const float4*)&lw[(k + 1) * OUT_FT + cg];
        float4 w2 = *(const float4*)&lw[(k + 2) * OUT_FT + cg];
        float4 w3 = *(const float4*)&lw[(k + 3) * OUT_FT + cg];
        FMA4(acc0, s0.x, w0); FMA4(acc0, s0.y, w1);
        FMA4(acc0, s0.z, w2); FMA4(acc0, s0.w, w3);
        FMA4(acc1, s1.x, w0); FMA4(acc1, s1.y, w1);
        FMA4(acc1, s1.z, w2); FMA4(acc1, s1.w, w3);
    }
#undef FMA4

    int row0 = base + r0;
    if (row0 < n) {
        ushort4 p = make_ushort4(f2bf(acc0.x), f2bf(acc0.y), f2bf(acc0.z), f2bf(acc0.w));
        *(ushort4*)&supb[(size_t)row0 * OUT_FT + cg] = p;
    }
    int row1 = base + r1;
    if (row1 < n) {
        ushort4 p = make_ushort4(f2bf(acc1.x), f2bf(acc1.y), f2bf(acc1.z), f2bf(acc1.w));
        *(ushort4*)&supb[(size_t)row1 * OUT_FT + cg] = p;
    }
}

// -------------------- scatter: thread = (edge, col-pair) --------------------
// 16 threads per edge; bf16x2 gather (4B) + packed v2f32 atomic add.
__global__ __launch_bounds__(256) void gcn_scatter2(const int* __restrict__ erow,
                                                    const int* __restrict__ ecol,
                                                    const float* __restrict__ eval,
                                                    const unsigned short* __restrict__ supb,
                                                    float* __restrict__ out,
                                                    int ne) {
    long long g = (long long)blockIdx.x * 256 + threadIdx.x;
    int e  = (int)(g >> 4);
    int cp = (int)(g & 15);          // column pair 0..15
    if (e >= ne) return;
    int   r = erow[e];
    int   c = ecol[e];
    float v = eval[e];
    unsigned pk = ((const unsigned*)(supb + (size_t)c * OUT_FT))[cp];
    float lo = __uint_as_float(pk << 16);            // element 2cp
    float hi = __uint_as_float(pk & 0xFFFF0000u);    // element 2cp+1
    float* dst = out + (size_t)r * OUT_FT + cp * 2;
#if __has_builtin(__builtin_amdgcn_global_atomic_fadd_v2f32)
    typedef float vf2 __attribute__((ext_vector_type(2)));
    __builtin_amdgcn_global_atomic_fadd_v2f32((vf2*)dst, (vf2){v * lo, v * hi});
#else
    atomicAdd(dst,     v * lo);
    atomicAdd(dst + 1, v * hi);
#endif
}

// -------------------- relu in place --------------------
__global__ __launch_bounds__(256) void gcn_relu(float4* __restrict__ out, int n4) {
    int i = blockIdx.x * 256 + threadIdx.x;
    if (i < n4) {
        float4 v = out[i];
        v.x = fmaxf(v.x, 0.f); v.y = fmaxf(v.y, 0.f);
        v.z = fmaxf(v.z, 0.f); v.w = fmaxf(v.w, 0.f);
        out[i] = v;
    }
}

extern "C" void kernel_launch(void* const* d_in, const int* in_sizes, int n_in,
                              void* d_out, int out_size, void* d_ws, size_t ws_size,
                              hipStream_t stream) {
    const float* seq  = (const float*)d_in[0];
    const float* w    = (const float*)d_in[1];
    const int*   erow = (const int*)d_in[2];
    const int*   ecol = (const int*)d_in[3];
    const float* eval = (const float*)d_in[4];
    float* out = (float*)d_out;
    unsigned short* supb = (unsigned short*)d_ws;   // n_nodes*32 bf16 = 6.4 MB

    const int n_nodes = in_sizes[0] / IN_FT;
    const int n_edges = in_sizes[2];

    // out accumulator must start at zero (harness poisons with 0xAA)
    hipMemsetAsync(d_out, 0, (size_t)out_size * sizeof(float), stream);

    // 1) support = seq @ weight  (bf16 output)
    int gemm_blocks = (n_nodes + GEMM_ROWS - 1) / GEMM_ROWS;
    gcn_gemm<<<gemm_blocks, 256, 0, stream>>>(seq, w, supb, n_nodes);

    // 2) scatter-add messages (packed atomics)
    long long work = (long long)n_edges * 16;
    gcn_scatter2<<<(int)((work + 255) / 256), 256, 0, stream>>>(
        erow, ecol, eval, supb, out, n_edges);

    // 3) relu
    int n4 = out_size / 4;
    gcn_relu<<<(n4 + 255) / 256, 256, 0, stream>>>((float4*)out, n4);
}

// Round 5
// 289.405 us; speedup vs baseline: 1.7691x; 1.5316x over previous
//
#include <hip/hip_runtime.h>
#include <hip/hip_bf16.h>

#define IN_FT  128
#define OUT_FT 32
#define GEMM_ROWS 64
#define PITCH  132

// float -> bf16 (round-to-nearest-even)
__device__ __forceinline__ unsigned short f2bf(float x) {
    union { float f; unsigned u; } v; v.f = x;
    unsigned r = v.u + 0x7FFFu + ((v.u >> 16) & 1u);
    return (unsigned short)(r >> 16);
}

// ---------- support(bf16) = seq @ weight ; also zeroes this block's out rows
__global__ __launch_bounds__(256) void gcn_gemm(const float* __restrict__ seq,
                                                const float* __restrict__ w,
                                                unsigned short* __restrict__ supb,
                                                float* __restrict__ out,
                                                int n) {
    __shared__ __align__(16) float lw[IN_FT * OUT_FT];
    __shared__ __align__(16) float ls[GEMM_ROWS * PITCH];

    const int tid = threadIdx.x;
    const int base = blockIdx.x * GEMM_ROWS;

    // zero this block's slice of out (replaces the separate memset dispatch)
    {
        float4 z = make_float4(0.f, 0.f, 0.f, 0.f);
        // 64 rows x 32 cols = 512 float4
        for (int i = tid; i < GEMM_ROWS * (OUT_FT / 4); i += 256) {
            int row = base + (i >> 3);
            if (row < n)
                ((float4*)(out + (size_t)row * OUT_FT))[i & 7] = z;
        }
    }

    for (int i = tid; i < (IN_FT * OUT_FT) / 4; i += 256)
        ((float4*)lw)[i] = ((const float4*)w)[i];

    for (int i = tid; i < GEMM_ROWS * (IN_FT / 4); i += 256) {
        int r  = i >> 5;
        int kc = i & 31;
        int row = base + r;
        float4 v = make_float4(0.f, 0.f, 0.f, 0.f);
        if (row < n)
            v = ((const float4*)(seq + (size_t)row * IN_FT))[kc];
        *(float4*)&ls[r * PITCH + kc * 4] = v;
    }
    __syncthreads();

    const int cg = (tid & 7) * 4;
    const int rp = tid >> 3;
    const int r0 = rp * 2, r1 = r0 + 1;

    float4 acc0 = make_float4(0.f, 0.f, 0.f, 0.f);
    float4 acc1 = make_float4(0.f, 0.f, 0.f, 0.f);

#define FMA4(acc, s, wv) \
    acc.x = fmaf((s), (wv).x, acc.x); \
    acc.y = fmaf((s), (wv).y, acc.y); \
    acc.z = fmaf((s), (wv).z, acc.z); \
    acc.w = fmaf((s), (wv).w, acc.w);

    for (int k = 0; k < IN_FT; k += 4) {
        float4 s0 = *(const float4*)&ls[r0 * PITCH + k];
        float4 s1 = *(const float4*)&ls[r1 * PITCH + k];
        float4 w0 = *(const float4*)&lw[(k + 0) * OUT_FT + cg];
        float4 w1 = *(const float4*)&lw[(k + 1) * OUT_FT + cg];
        float4 w2 = *(const float4*)&lw[(k + 2) * OUT_FT + cg];
        float4 w3 = *(const float4*)&lw[(k + 3) * OUT_FT + cg];
        FMA4(acc0, s0.x, w0); FMA4(acc0, s0.y, w1);
        FMA4(acc0, s0.z, w2); FMA4(acc0, s0.w, w3);
        FMA4(acc1, s1.x, w0); FMA4(acc1, s1.y, w1);
        FMA4(acc1, s1.z, w2); FMA4(acc1, s1.w, w3);
    }
#undef FMA4

    int row0 = base + r0;
    if (row0 < n) {
        ushort4 p = make_ushort4(f2bf(acc0.x), f2bf(acc0.y), f2bf(acc0.z), f2bf(acc0.w));
        *(ushort4*)&supb[(size_t)row0 * OUT_FT + cg] = p;
    }
    int row1 = base + r1;
    if (row1 < n) {
        ushort4 p = make_ushort4(f2bf(acc1.x), f2bf(acc1.y), f2bf(acc1.z), f2bf(acc1.w));
        *(ushort4*)&supb[(size_t)row1 * OUT_FT + cg] = p;
    }
}

// ---------- scatter: thread = (edge, col); bf16 gather + scalar fp32 atomic
__global__ __launch_bounds__(256) void gcn_scatter3(const int* __restrict__ erow,
                                                    const int* __restrict__ ecol,
                                                    const float* __restrict__ eval,
                                                    const unsigned short* __restrict__ supb,
                                                    float* __restrict__ out,
                                                    int ne) {
    long long g = (long long)blockIdx.x * 256 + threadIdx.x;
    int e = (int)(g >> 5);
    int c = (int)(g & 31);
    if (e >= ne) return;
    int   r  = erow[e];
    int   cl = ecol[e];
    float v  = eval[e];
    unsigned short b = supb[(size_t)cl * OUT_FT + c];
    float s = __uint_as_float(((unsigned)b) << 16);
    atomicAdd(out + (size_t)r * OUT_FT + c, v * s);
}

// ---------- relu in place ----------
__global__ __launch_bounds__(256) void gcn_relu(float4* __restrict__ out, int n4) {
    int i = blockIdx.x * 256 + threadIdx.x;
    if (i < n4) {
        float4 v = out[i];
        v.x = fmaxf(v.x, 0.f); v.y = fmaxf(v.y, 0.f);
        v.z = fmaxf(v.z, 0.f); v.w = fmaxf(v.w, 0.f);
        out[i] = v;
    }
}

extern "C" void kernel_launch(void* const* d_in, const int* in_sizes, int n_in,
                              void* d_out, int out_size, void* d_ws, size_t ws_size,
                              hipStream_t stream) {
    const float* seq  = (const float*)d_in[0];
    const float* w    = (const float*)d_in[1];
    const int*   erow = (const int*)d_in[2];
    const int*   ecol = (const int*)d_in[3];
    const float* eval = (const float*)d_in[4];
    float* out = (float*)d_out;
    unsigned short* supb = (unsigned short*)d_ws;   // n_nodes*32 bf16 = 6.4 MB

    const int n_nodes = in_sizes[0] / IN_FT;
    const int n_edges = in_sizes[2];

    // 1) support = seq @ weight (bf16 out) + zero d_out
    int gemm_blocks = (n_nodes + GEMM_ROWS - 1) / GEMM_ROWS;
    gcn_gemm<<<gemm_blocks, 256, 0, stream>>>(seq, w, supb, out, n_nodes);

    // 2) scatter-add messages (scalar fp32 atomics, bf16 gathers)
    long long work = (long long)n_edges * OUT_FT;
    gcn_scatter3<<<(int)((work + 255) / 256), 256, 0, stream>>>(
        erow, ecol, eval, supb, out, n_edges);

    // 3) relu
    int n4 = out_size / 4;
    gcn_relu<<<(n4 + 255) / 256, 256, 0, stream>>>((float4*)out, n4);
}

// Round 6
// 276.801 us; speedup vs baseline: 1.8496x; 1.0455x over previous
//
#include <hip/hip_runtime.h>
#include <hip/hip_bf16.h>

#define IN_FT  128
#define OUT_FT 32

typedef __attribute__((ext_vector_type(8))) short bf16x8;
typedef __attribute__((ext_vector_type(4))) float f32x4;

// float -> bf16 (round-to-nearest-even)
__device__ __forceinline__ unsigned short f2bf(float x) {
    union { float f; unsigned u; } v; v.f = x;
    unsigned r = v.u + 0x7FFFu + ((v.u >> 16) & 1u);
    return (unsigned short)(r >> 16);
}
__device__ __forceinline__ float bf2f(unsigned short b) {
    return __uint_as_float(((unsigned)b) << 16);
}

// ---------------- MFMA GEMM: sup = seq @ w, bf16, col-split output ----------
// Block = 256 thr = 4 waves; wave computes 16 rows x 32 cols via
// 2 accumulators x 4 k-steps of mfma_f32_16x16x32_bf16.
// Weight staged in LDS pre-swizzled to exact B-fragment order:
//   wb[tile][ktile][lane][j] = w[k = ktile*32 + (lane>>4)*8 + j][col = (lane&15) + tile*16]
// so the fragment load is a conflict-free ds_read_b128 at lane*16.
__global__ __launch_bounds__(256) void gcn_gemm_mfma(const float* __restrict__ seq,
                                                     const float* __restrict__ w,
                                                     unsigned short* __restrict__ sup0,
                                                     unsigned short* __restrict__ sup1,
                                                     float* __restrict__ out,
                                                     int n) {
    __shared__ __align__(16) unsigned short wb[2][4][64][8];   // 16 KB
    const int t = threadIdx.x;
    const int base = blockIdx.x * 64;

    // build swizzled weight fragments (8192 elems, 32/thread)
    for (int i = t; i < 2 * 4 * 64 * 8; i += 256) {
        int j    = i & 7;
        int lane = (i >> 3) & 63;
        int kt   = (i >> 9) & 3;
        int tile = i >> 11;
        int k    = kt * 32 + (lane >> 4) * 8 + j;
        int c    = (lane & 15) + tile * 16;
        wb[tile][kt][lane][j] = f2bf(w[k * OUT_FT + c]);
    }

    // zero this block's out rows (replaces memset dispatch)
    {
        float4 z = make_float4(0.f, 0.f, 0.f, 0.f);
        for (int i = t; i < 64 * (OUT_FT / 4); i += 256) {
            int row = base + (i >> 3);
            if (row < n)
                ((float4*)(out + (size_t)row * OUT_FT))[i & 7] = z;
        }
    }
    __syncthreads();

    const int wave = t >> 6;
    const int lane = t & 63;
    const int m    = lane & 15;
    const int quad = lane >> 4;

    const int row = base + wave * 16 + m;
    const bool rv = (row < n);
    const float* arow = seq + (size_t)row * IN_FT;

    f32x4 acc0 = {0.f, 0.f, 0.f, 0.f};
    f32x4 acc1 = {0.f, 0.f, 0.f, 0.f};

    for (int kt = 0; kt < 4; ++kt) {
        int k0 = kt * 32 + quad * 8;
        bf16x8 a;
        if (rv) {
            float4 lo = *(const float4*)(arow + k0);
            float4 hi = *(const float4*)(arow + k0 + 4);
            a[0] = (short)f2bf(lo.x); a[1] = (short)f2bf(lo.y);
            a[2] = (short)f2bf(lo.z); a[3] = (short)f2bf(lo.w);
            a[4] = (short)f2bf(hi.x); a[5] = (short)f2bf(hi.y);
            a[6] = (short)f2bf(hi.z); a[7] = (short)f2bf(hi.w);
        } else {
            a = (bf16x8)0;
        }
        bf16x8 b0 = *(const bf16x8*)&wb[0][kt][lane][0];
        bf16x8 b1 = *(const bf16x8*)&wb[1][kt][lane][0];
        acc0 = __builtin_amdgcn_mfma_f32_16x16x32_bf16(a, b0, acc0, 0, 0, 0);
        acc1 = __builtin_amdgcn_mfma_f32_16x16x32_bf16(a, b1, acc1, 0, 0, 0);
    }

    // C/D layout: col = lane&15, row = quad*4 + reg  (m89/m91-verified)
    for (int i = 0; i < 4; ++i) {
        int ro = base + wave * 16 + quad * 4 + i;
        if (ro < n) {
            sup0[(size_t)ro * 16 + m] = f2bf(acc0[i]);
            sup1[(size_t)ro * 16 + m] = f2bf(acc1[i]);
        }
    }
}

// ---------- scatter: 16 threads/edge over one col-half (L2-resident table) --
__global__ __launch_bounds__(256) void gcn_scatter16(const int* __restrict__ erow,
                                                     const int* __restrict__ ecol,
                                                     const float* __restrict__ eval,
                                                     const unsigned short* __restrict__ supt,
                                                     float* __restrict__ out,
                                                     int ne, int cbase) {
    long long g = (long long)blockIdx.x * 256 + threadIdx.x;
    int e = (int)(g >> 4);
    int c = (int)(g & 15);
    if (e >= ne) return;
    int   r  = erow[e];
    int   cl = ecol[e];
    float v  = eval[e];
    float s  = bf2f(supt[(size_t)cl * 16 + c]);
    atomicAdd(out + (size_t)r * OUT_FT + cbase + c, v * s);
}

// ---------- relu in place ----------
__global__ __launch_bounds__(256) void gcn_relu(float4* __restrict__ out, int n4) {
    int i = blockIdx.x * 256 + threadIdx.x;
    if (i < n4) {
        float4 v = out[i];
        v.x = fmaxf(v.x, 0.f); v.y = fmaxf(v.y, 0.f);
        v.z = fmaxf(v.z, 0.f); v.w = fmaxf(v.w, 0.f);
        out[i] = v;
    }
}

extern "C" void kernel_launch(void* const* d_in, const int* in_sizes, int n_in,
                              void* d_out, int out_size, void* d_ws, size_t ws_size,
                              hipStream_t stream) {
    const float* seq  = (const float*)d_in[0];
    const float* w    = (const float*)d_in[1];
    const int*   erow = (const int*)d_in[2];
    const int*   ecol = (const int*)d_in[3];
    const float* eval = (const float*)d_in[4];
    float* out = (float*)d_out;

    const int n_nodes = in_sizes[0] / IN_FT;
    const int n_edges = in_sizes[2];

    // col-split sup tables: each n_nodes*16 bf16 = 3.2 MB (fits per-XCD L2)
    unsigned short* sup0 = (unsigned short*)d_ws;
    unsigned short* sup1 = sup0 + (size_t)n_nodes * 16;

    // 1) sup = seq @ w (bf16, MFMA) + zero d_out
    int gemm_blocks = (n_nodes + 63) / 64;
    gcn_gemm_mfma<<<gemm_blocks, 256, 0, stream>>>(seq, w, sup0, sup1, out, n_nodes);

    // 2) scatter-add, two col-half passes (keeps gather table L2-resident)
    long long work = (long long)n_edges * 16;
    int sc_blocks = (int)((work + 255) / 256);
    gcn_scatter16<<<sc_blocks, 256, 0, stream>>>(erow, ecol, eval, sup0, out,
                                                 n_edges, 0);
    gcn_scatter16<<<sc_blocks, 256, 0, stream>>>(erow, ecol, eval, sup1, out,
                                                 n_edges, 16);

    // 3) relu
    int n4 = out_size / 4;
    gcn_relu<<<(n4 + 255) / 256, 256, 0, stream>>>((float4*)out, n4);
}

// Round 9
// 201.808 us; speedup vs baseline: 2.5370x; 1.3716x over previous
//
#include <hip/hip_runtime.h>
#include <hip/hip_bf16.h>
#include <hip/hip_fp16.h>

#define IN_FT  128
#define OUT_FT 32

typedef _Float16 f16x8 __attribute__((ext_vector_type(8)));
typedef _Float16 f16x2 __attribute__((ext_vector_type(2)));
typedef __attribute__((ext_vector_type(4))) float f32x4;

union H2 { unsigned u; _Float16 h[2]; };

// ---- one-shot: build swizzled f16 weight fragment table (16 KB, L2-hot) ----
// wtab[tile][kt][lane][j] = w[kt*32 + (lane>>4)*8 + j][(lane&15) + tile*16]
__global__ __launch_bounds__(256) void gcn_swz(const float* __restrict__ w,
                                               _Float16* __restrict__ wtab) {
    int t = threadIdx.x;
    for (int i = t; i < 2 * 4 * 64 * 8; i += 256) {
        int j    = i & 7;
        int lane = (i >> 3) & 63;
        int kt   = (i >> 9) & 3;
        int tile = i >> 11;
        int k    = kt * 32 + (lane >> 4) * 8 + j;
        int c    = (lane & 15) + tile * 16;
        wtab[i] = (_Float16)w[k * OUT_FT + c];
    }
}

// ---- sup(f16) = seq @ w via MFMA; also zeroes the f16 accumulator slice ----
__global__ __launch_bounds__(256) void gcn_gemm_mfma(const float* __restrict__ seq,
                                                     const _Float16* __restrict__ wtab,
                                                     unsigned short* __restrict__ sup,
                                                     unsigned short* __restrict__ accb,
                                                     int n) {
    const int t    = threadIdx.x;
    const int base = blockIdx.x * 64;

    // zero this block's 64-row slice of the f16 accumulator (64 x 64 B)
    {
        int row = base + (t >> 2);
        if (row < n) {
            uint4 z = make_uint4(0, 0, 0, 0);
            ((uint4*)(accb + (size_t)row * OUT_FT))[t & 3] = z;
        }
    }

    const int wave = t >> 6;
    const int lane = t & 63;
    const int m    = lane & 15;
    const int quad = lane >> 4;

    const int row = base + wave * 16 + m;
    const bool rv = (row < n);
    const float* arow = seq + (size_t)row * IN_FT;

    const f16x8* wt = (const f16x8*)wtab;

    f32x4 acc0 = {0.f, 0.f, 0.f, 0.f};
    f32x4 acc1 = {0.f, 0.f, 0.f, 0.f};

    for (int kt = 0; kt < 4; ++kt) {
        int k0 = kt * 32 + quad * 8;
        f16x8 a = (f16x8)0;
        if (rv) {
            float4 lo = *(const float4*)(arow + k0);
            float4 hi = *(const float4*)(arow + k0 + 4);
            a[0] = (_Float16)lo.x; a[1] = (_Float16)lo.y;
            a[2] = (_Float16)lo.z; a[3] = (_Float16)lo.w;
            a[4] = (_Float16)hi.x; a[5] = (_Float16)hi.y;
            a[6] = (_Float16)hi.z; a[7] = (_Float16)hi.w;
        }
        f16x8 b0 = wt[(0 * 4 + kt) * 64 + lane];
        f16x8 b1 = wt[(1 * 4 + kt) * 64 + lane];
        acc0 = __builtin_amdgcn_mfma_f32_16x16x32_f16(a, b0, acc0, 0, 0, 0);
        acc1 = __builtin_amdgcn_mfma_f32_16x16x32_f16(a, b1, acc1, 0, 0, 0);
    }

    // C/D layout: col = lane&15, row = quad*4 + reg
    for (int i = 0; i < 4; ++i) {
        int ro = base + wave * 16 + quad * 4 + i;
        if (ro < n) {
            _Float16 h0 = (_Float16)acc0[i];
            _Float16 h1 = (_Float16)acc1[i];
            sup[(size_t)ro * OUT_FT + m]      = *(unsigned short*)&h0;
            sup[(size_t)ro * OUT_FT + 16 + m] = *(unsigned short*)&h1;
        }
    }
}

// ---- scatter: thread = (edge, col-pair); ONE pk_add_f16 atomic per thread --
__global__ __launch_bounds__(256) void gcn_scatter_h2(const int* __restrict__ erow,
                                                      const int* __restrict__ ecol,
                                                      const float* __restrict__ eval,
                                                      const unsigned short* __restrict__ sup,
                                                      unsigned short* __restrict__ accb,
                                                      int ne) {
    long long g = (long long)blockIdx.x * 256 + threadIdx.x;
    int e  = (int)(g >> 4);
    int cp = (int)(g & 15);
    if (e >= ne) return;
    int   r  = erow[e];
    int   cl = ecol[e];
    float v  = eval[e];
    H2 s; s.u = ((const unsigned*)(sup + (size_t)cl * OUT_FT))[cp];
    f16x2 msg;
    msg[0] = (_Float16)(v * (float)s.h[0]);
    msg[1] = (_Float16)(v * (float)s.h[1]);
    f16x2* dst = (f16x2*)(accb + (size_t)r * OUT_FT + cp * 2);
#if defined(__HIP_DEVICE_COMPILE__)
    // global_atomic_pk_add_f16: one 4B atomic deposits two f16 adds
    __builtin_amdgcn_global_atomic_fadd_v2f16(dst, msg);
#else
    (void)dst; (void)msg;   // host pass parses but never executes kernels
#endif
}

// ---- expand f16 accumulator -> fp32 out with relu ----
__global__ __launch_bounds__(256) void gcn_relu_h2(const unsigned* __restrict__ accb,
                                                   float4* __restrict__ out, int nq) {
    int i = blockIdx.x * 256 + threadIdx.x;
    if (i >= nq) return;
    uint2 p = ((const uint2*)accb)[i];
    H2 a, b; a.u = p.x; b.u = p.y;
    float4 o;
    o.x = fmaxf((float)a.h[0], 0.f);
    o.y = fmaxf((float)a.h[1], 0.f);
    o.z = fmaxf((float)b.h[0], 0.f);
    o.w = fmaxf((float)b.h[1], 0.f);
    out[i] = o;
}

extern "C" void kernel_launch(void* const* d_in, const int* in_sizes, int n_in,
                              void* d_out, int out_size, void* d_ws, size_t ws_size,
                              hipStream_t stream) {
    const float* seq  = (const float*)d_in[0];
    const float* w    = (const float*)d_in[1];
    const int*   erow = (const int*)d_in[2];
    const int*   ecol = (const int*)d_in[3];
    const float* eval = (const float*)d_in[4];
    float* out = (float*)d_out;

    const int n_nodes = in_sizes[0] / IN_FT;
    const int n_edges = in_sizes[2];

    // workspace: sup f16 (6.4 MB) | acc f16 (6.4 MB) | wtab (16 KB)
    unsigned short* sup  = (unsigned short*)d_ws;
    unsigned short* accb = sup + (size_t)n_nodes * OUT_FT;
    _Float16*       wtab = (_Float16*)(accb + (size_t)n_nodes * OUT_FT);

    // 1) swizzled weight table
    gcn_swz<<<1, 256, 0, stream>>>(w, wtab);

    // 2) sup = seq @ w (f16) + zero acc
    int gemm_blocks = (n_nodes + 63) / 64;
    gcn_gemm_mfma<<<gemm_blocks, 256, 0, stream>>>(seq, wtab, sup, accb, n_nodes);

    // 3) scatter: one packed-f16 atomic per (edge, col-pair)
    long long work = (long long)n_edges * 16;
    gcn_scatter_h2<<<(int)((work + 255) / 256), 256, 0, stream>>>(
        erow, ecol, eval, sup, accb, n_edges);

    // 4) relu-expand to fp32
    int nq = out_size / 4;
    gcn_relu_h2<<<(nq + 255) / 256, 256, 0, stream>>>((const unsigned*)accb,
                                                      (float4*)out, nq);
}

// Round 10
// 200.779 us; speedup vs baseline: 2.5500x; 1.0051x over previous
//
#include <hip/hip_runtime.h>
#include <hip/hip_bf16.h>
#include <hip/hip_fp16.h>

#define IN_FT  128
#define OUT_FT 32
#define APITCH 136   // f16 pitch for A tile: 272B rows, benign b128 bank pattern

typedef _Float16 f16x8 __attribute__((ext_vector_type(8)));
typedef _Float16 f16x4 __attribute__((ext_vector_type(4)));
typedef _Float16 f16x2 __attribute__((ext_vector_type(2)));
typedef __attribute__((ext_vector_type(4))) float f32x4;

union H2 { unsigned u; _Float16 h[2]; };

// ---- one-shot: build swizzled f16 weight fragment table (16 KB, L2-hot) ----
// wtab[tile][kt][lane][j] = w[kt*32 + (lane>>4)*8 + j][(lane&15) + tile*16]
__global__ __launch_bounds__(256) void gcn_swz(const float* __restrict__ w,
                                               _Float16* __restrict__ wtab) {
    int t = threadIdx.x;
    for (int i = t; i < 2 * 4 * 64 * 8; i += 256) {
        int j    = i & 7;
        int lane = (i >> 3) & 63;
        int kt   = (i >> 9) & 3;
        int tile = i >> 11;
        int k    = kt * 32 + (lane >> 4) * 8 + j;
        int c    = (lane & 15) + tile * 16;
        wtab[i] = (_Float16)w[k * OUT_FT + c];
    }
}

// ---- sup(f16) = seq @ w via MFMA with LDS-staged coalesced A ----
// Covers rows [nbase, nbase+64*gridDim.x); also zeroes accb slice.
__global__ __launch_bounds__(256) void gcn_gemm_mfma(const float* __restrict__ seq,
                                                     const _Float16* __restrict__ wtab,
                                                     unsigned short* __restrict__ sup,
                                                     unsigned short* __restrict__ accb,
                                                     int nbase, int n) {
    __shared__ __align__(16) _Float16 at[64 * APITCH];   // 17 KB
    const int t    = threadIdx.x;
    const int base = nbase + blockIdx.x * 64;

    // zero this block's 64-row slice of the f16 accumulator (64 x 64 B)
    {
        int row = base + (t >> 2);
        if (row < n) {
            uint4 z = make_uint4(0, 0, 0, 0);
            ((uint4*)(accb + (size_t)row * OUT_FT))[t & 3] = z;
        }
    }

    // stage A tile: 64 rows x 128 f32 -> f16, coalesced global reads.
    // iteration unit: (row_l, c) ; c indexes 8-float (32B) segments.
    for (int it = 0; it < 4; ++it) {
        int i     = it * 256 + t;
        int row_l = i >> 4;
        int c     = i & 15;
        int row   = base + row_l;
        f16x8 v = (f16x8)0;
        if (row < n) {
            const float4* p = (const float4*)(seq + (size_t)row * IN_FT + c * 8);
            float4 lo = p[0], hi = p[1];
            v[0] = (_Float16)lo.x; v[1] = (_Float16)lo.y;
            v[2] = (_Float16)lo.z; v[3] = (_Float16)lo.w;
            v[4] = (_Float16)hi.x; v[5] = (_Float16)hi.y;
            v[6] = (_Float16)hi.z; v[7] = (_Float16)hi.w;
        }
        *(f16x8*)&at[row_l * APITCH + c * 8] = v;
    }
    __syncthreads();

    const int wave = t >> 6;
    const int lane = t & 63;
    const int m    = lane & 15;
    const int quad = lane >> 4;

    const f16x8* wt = (const f16x8*)wtab;
    const int arow_l = wave * 16 + m;

    f32x4 acc0 = {0.f, 0.f, 0.f, 0.f};
    f32x4 acc1 = {0.f, 0.f, 0.f, 0.f};

    for (int kt = 0; kt < 4; ++kt) {
        f16x8 a = *(const f16x8*)&at[arow_l * APITCH + kt * 32 + quad * 8];
        f16x8 b0 = wt[(0 * 4 + kt) * 64 + lane];
        f16x8 b1 = wt[(1 * 4 + kt) * 64 + lane];
        acc0 = __builtin_amdgcn_mfma_f32_16x16x32_f16(a, b0, acc0, 0, 0, 0);
        acc1 = __builtin_amdgcn_mfma_f32_16x16x32_f16(a, b1, acc1, 0, 0, 0);
    }

    // C/D layout: col = lane&15, row = quad*4 + reg
    for (int i = 0; i < 4; ++i) {
        int ro = base + wave * 16 + quad * 4 + i;
        if (ro < n) {
            _Float16 h0 = (_Float16)acc0[i];
            _Float16 h1 = (_Float16)acc1[i];
            sup[(size_t)ro * OUT_FT + m]      = *(unsigned short*)&h0;
            sup[(size_t)ro * OUT_FT + 16 + m] = *(unsigned short*)&h1;
        }
    }
}

// ---- scatter: thread = (edge, col-pair); ONE pk_add_f16 atomic per thread --
__global__ __launch_bounds__(256) void gcn_scatter_h2(const int* __restrict__ erow,
                                                      const int* __restrict__ ecol,
                                                      const float* __restrict__ eval,
                                                      const unsigned short* __restrict__ sup,
                                                      unsigned short* __restrict__ accb,
                                                      int ebase, int eend) {
    long long g = (long long)blockIdx.x * 256 + threadIdx.x;
    int e  = ebase + (int)(g >> 4);
    int cp = (int)(g & 15);
    if (e >= eend) return;
    int   r  = erow[e];
    int   cl = ecol[e];
    float v  = eval[e];
    H2 s; s.u = ((const unsigned*)(sup + (size_t)cl * OUT_FT))[cp];
    f16x2 msg;
    msg[0] = (_Float16)(v * (float)s.h[0]);
    msg[1] = (_Float16)(v * (float)s.h[1]);
    f16x2* dst = (f16x2*)(accb + (size_t)r * OUT_FT + cp * 2);
#if defined(__HIP_DEVICE_COMPILE__)
    __builtin_amdgcn_global_atomic_fadd_v2f16(dst, msg);
#else
    (void)dst; (void)msg;
#endif
}

// ---- expand f16 accumulator -> fp32 out with relu ----
__global__ __launch_bounds__(256) void gcn_relu_h2(const unsigned* __restrict__ accb,
                                                   float4* __restrict__ out, int nq) {
    int i = blockIdx.x * 256 + threadIdx.x;
    if (i >= nq) return;
    uint2 p = ((const uint2*)accb)[i];
    H2 a, b; a.u = p.x; b.u = p.y;
    float4 o;
    o.x = fmaxf((float)a.h[0], 0.f);
    o.y = fmaxf((float)a.h[1], 0.f);
    o.z = fmaxf((float)b.h[0], 0.f);
    o.w = fmaxf((float)b.h[1], 0.f);
    out[i] = o;
}

extern "C" void kernel_launch(void* const* d_in, const int* in_sizes, int n_in,
                              void* d_out, int out_size, void* d_ws, size_t ws_size,
                              hipStream_t stream) {
    const float* seq  = (const float*)d_in[0];
    const float* w    = (const float*)d_in[1];
    const int*   erow = (const int*)d_in[2];
    const int*   ecol = (const int*)d_in[3];
    const float* eval = (const float*)d_in[4];
    float* out = (float*)d_out;

    const int n_nodes = in_sizes[0] / IN_FT;
    const int n_edges = in_sizes[2];

    // workspace: sup f16 (6.4 MB) | acc f16 (6.4 MB) | wtab (16 KB)
    unsigned short* sup  = (unsigned short*)d_ws;
    unsigned short* accb = sup + (size_t)n_nodes * OUT_FT;
    _Float16*       wtab = (_Float16*)(accb + (size_t)n_nodes * OUT_FT);

    // 1) swizzled weight table
    gcn_swz<<<1, 256, 0, stream>>>(w, wtab);

    // 2) sup = seq @ w (f16) + zero acc — two half-node dispatches
    int gemm_blocks = (n_nodes + 63) / 64;
    int gb0 = gemm_blocks / 2;
    int gb1 = gemm_blocks - gb0;
    gcn_gemm_mfma<<<gb0, 256, 0, stream>>>(seq, wtab, sup, accb, 0, n_nodes);
    gcn_gemm_mfma<<<gb1, 256, 0, stream>>>(seq, wtab, sup, accb, gb0 * 64, n_nodes);

    // 3) scatter — two half-edge dispatches (visibility: anything >=46us must
    //    now show in top-5)
    int eh = n_edges / 2;
    long long w0 = (long long)eh * 16;
    long long w1 = (long long)(n_edges - eh) * 16;
    gcn_scatter_h2<<<(int)((w0 + 255) / 256), 256, 0, stream>>>(
        erow, ecol, eval, sup, accb, 0, eh);
    gcn_scatter_h2<<<(int)((w1 + 255) / 256), 256, 0, stream>>>(
        erow, ecol, eval, sup, accb, eh, n_edges);

    // 4) relu-expand to fp32
    int nq = out_size / 4;
    gcn_relu_h2<<<(nq + 255) / 256, 256, 0, stream>>>((const unsigned*)accb,
                                                      (float4*)out, nq);
}